// Round 1
// baseline (491.562 us; speedup 1.0000x reference)
//
#include <hip/hip_runtime.h>
#include <cstddef>

#define B_    32
#define N_    1024
#define E_    4096
#define A_    16
#define FIN_  16
#define H_    64
#define MID_  208
#define NODES (B_ * N_)      // 32768
#define NEDGE (B_ * E_)      // 131072
#define ROWS  (B_ * A_ * N_) // 524288
#define AN_   (A_ * N_)      // 16384

// ---------------- CSR build (edges keyed by dst) ----------------
__global__ __launch_bounds__(256) void k_hist(const int* __restrict__ el,
                                              int* __restrict__ counts) {
  int e = blockIdx.x * 256 + threadIdx.x;        // 0..131071
  int b = e >> 12;
  int dl = el[b * (2 * E_) + E_ + (e & (E_ - 1))];
  atomicAdd(&counts[b * N_ + dl], 1);
}

__global__ __launch_bounds__(1024) void k_scan(const int* __restrict__ counts,
                                               int* __restrict__ rowptr,
                                               int* __restrict__ cursor) {
  __shared__ int part[1024];
  int t = threadIdx.x;
  int base = t * 32;
  int pre[32];
  int s = 0;
#pragma unroll
  for (int i = 0; i < 32; i++) { pre[i] = s; s += counts[base + i]; }
  part[t] = s;
  __syncthreads();
  for (int off = 1; off < 1024; off <<= 1) {
    int v = (t >= off) ? part[t - off] : 0;
    __syncthreads();
    part[t] += v;
    __syncthreads();
  }
  int prev = (t == 0) ? 0 : part[t - 1];
#pragma unroll
  for (int i = 0; i < 32; i++) {
    int r = prev + pre[i];
    rowptr[base + i] = r;
    cursor[base + i] = r;
  }
}

__global__ __launch_bounds__(256) void k_scatter(const int* __restrict__ el,
                                                 int* __restrict__ cursor,
                                                 int* __restrict__ ssrc) {
  int e = blockIdx.x * 256 + threadIdx.x;
  int b = e >> 12;
  int le = e & (E_ - 1);
  int sl = el[b * (2 * E_) + le];
  int dl = el[b * (2 * E_) + E_ + le];
  int pos = atomicAdd(&cursor[b * N_ + dl], 1);
  ssrc[pos] = b * N_ + sl;
}

// ---------------- GIN layer: wave per node ----------------
// out = relu(LN(agg @ W + bias) * g + beta); agg = sum_{e: dst==node} x[src]
template <int FINT, bool COPYIN>
__global__ __launch_bounds__(256) void k_layer(const float* __restrict__ xin, int xstride, int in_off,
                                               float* __restrict__ xc, int out_off,
                                               const int* __restrict__ rowptr,
                                               const int* __restrict__ counts,
                                               const int* __restrict__ ssrc,
                                               const float* __restrict__ W,
                                               const float* __restrict__ bias,
                                               const float* __restrict__ g,
                                               const float* __restrict__ beta) {
  __shared__ float Ws[FINT * 64];
  __shared__ float aggs[4][64];
  int t = threadIdx.x;
  for (int i = t; i < FINT * 64; i += 256) Ws[i] = W[i];
  int lane = t & 63, w = t >> 6;
  int node = blockIdx.x * 4 + w;
  int r0 = rowptr[node];
  int deg = counts[node];
  float aggf = 0.f;
  if (lane < FINT) {
    for (int e = 0; e < deg; e++) {
      int s = ssrc[r0 + e];
      aggf += xin[s * xstride + in_off + lane];
    }
  }
  aggs[w][lane] = (lane < FINT) ? aggf : 0.f;
  __syncthreads();
  float y = bias[lane];
#pragma unroll
  for (int f = 0; f < FINT; f++) {
    y = fmaf(aggs[w][f], Ws[f * 64 + lane], y);
  }
  // LayerNorm over the 64 outputs == the wave's 64 lanes
  float m = y;
#pragma unroll
  for (int o = 32; o > 0; o >>= 1) m += __shfl_xor(m, o);
  m *= (1.f / 64.f);
  float d = y - m;
  float vv = d * d;
#pragma unroll
  for (int o = 32; o > 0; o >>= 1) vv += __shfl_xor(vv, o);
  vv *= (1.f / 64.f);
  float outv = fmaxf(d * rsqrtf(vv + 1e-5f) * g[lane] + beta[lane], 0.f);
  xc[node * MID_ + out_off + lane] = outv;
  if (COPYIN) {
    if (lane < FIN_) xc[node * MID_ + lane] = xin[node * FIN_ + lane];
  }
}

// ---------------- pA: 512 agent rows x W1[0:208] ----------------
__global__ __launch_bounds__(256) void k_pA(const float* __restrict__ xc,
                                            const int* __restrict__ loc,
                                            const float* __restrict__ W1,
                                            float* __restrict__ pA) {
  int blk = blockIdx.x;            // b*16 + a
  int b = blk >> 4;
  __shared__ float xr[MID_];
  int t = threadIdx.x;
  int node = b * N_ + loc[blk];
  if (t < MID_) xr[t] = xc[node * MID_ + t];
  __syncthreads();
  if (t < MID_) {
    float acc = 0.f;
    for (int i = 0; i < MID_; i++) acc = fmaf(xr[i], W1[i * MID_ + t], acc);
    pA[blk * MID_ + t] = acc;
  }
}

// ---------------- cu = eW @ W1[416:480], base = eb @ W1[416:480] + b1 ----------------
__global__ __launch_bounds__(256) void k_cu(const float* __restrict__ W1,
                                            const float* __restrict__ eW,
                                            const float* __restrict__ eb,
                                            const float* __restrict__ b1,
                                            float* __restrict__ cu,
                                            float* __restrict__ base) {
  int j = threadIdx.x;
  if (j < MID_) {
    float c = 0.f, bs = 0.f;
    for (int k = 0; k < H_; k++) {
      float w = W1[(2 * MID_ + k) * MID_ + j];
      c = fmaf(eW[k], w, c);
      bs = fmaf(eb[k], w, bs);
    }
    cu[j] = c;
    base[j] = bs + b1[j];
  }
}

// ---------------- pB GEMM: [32768,208] @ W1[208:416] -> [32768,208] ----------------
// BM=64, BN=256 (208 padded), BK=16, 256 threads, thread tile 4x16
#define ASTR 72
__global__ __launch_bounds__(256) void k_pB(const float* __restrict__ xc,
                                            const float* __restrict__ W1,
                                            float* __restrict__ pB) {
  __shared__ float As[16 * ASTR];
  __shared__ float Bs[16 * 256];
  int t = threadIdx.x;
  int row0 = blockIdx.x * 64;
  int rm = t & 15, rn = t >> 4;
  float acc[4][16];
#pragma unroll
  for (int i = 0; i < 4; i++)
#pragma unroll
    for (int j = 0; j < 16; j++) acc[i][j] = 0.f;

  int arow = t & 63, akq = t >> 6;

  for (int kt = 0; kt < 13; kt++) {
    int k0 = kt * 16;
    // stage A tile (64 rows x 16 k), k-major in LDS
    {
      const float4 v = *(const float4*)(xc + (size_t)(row0 + arow) * MID_ + k0 + akq * 4);
      As[(akq * 4 + 0) * ASTR + arow] = v.x;
      As[(akq * 4 + 1) * ASTR + arow] = v.y;
      As[(akq * 4 + 2) * ASTR + arow] = v.z;
      As[(akq * 4 + 3) * ASTR + arow] = v.w;
    }
    // stage B tile (16 k x 208 cols, zero-padded to 256)
    for (int idx = t; idx < 16 * 256; idx += 256) {
      int kk = idx >> 8, j = idx & 255;
      Bs[idx] = (j < MID_) ? W1[(size_t)(MID_ + k0 + kk) * MID_ + j] : 0.f;
    }
    __syncthreads();
#pragma unroll 4
    for (int kk = 0; kk < 16; kk++) {
      float4 a4 = *(const float4*)&As[kk * ASTR + rm * 4];
      const float* bp = &Bs[kk * 256 + rn * 16];
      float4 b0 = *(const float4*)(bp);
      float4 b1v = *(const float4*)(bp + 4);
      float4 b2v = *(const float4*)(bp + 8);
      float4 b3v = *(const float4*)(bp + 12);
      float av[4] = {a4.x, a4.y, a4.z, a4.w};
      float bv[16] = {b0.x, b0.y, b0.z, b0.w, b1v.x, b1v.y, b1v.z, b1v.w,
                      b2v.x, b2v.y, b2v.z, b2v.w, b3v.x, b3v.y, b3v.z, b3v.w};
#pragma unroll
      for (int i = 0; i < 4; i++)
#pragma unroll
        for (int j = 0; j < 16; j++) acc[i][j] = fmaf(av[i], bv[j], acc[i][j]);
    }
    __syncthreads();
  }
  if (rn < 13) {
#pragma unroll
    for (int i = 0; i < 4; i++) {
      float* dst = pB + (size_t)(row0 + rm * 4 + i) * MID_ + rn * 16;
#pragma unroll
      for (int q = 0; q < 4; q++) {
        *(float4*)(dst + q * 4) =
            make_float4(acc[i][q * 4 + 0], acc[i][q * 4 + 1], acc[i][q * 4 + 2], acc[i][q * 4 + 3]);
      }
    }
  }
}

// ---------------- BN stats: per-feature sum / sumsq over all rows ----------------
// grid (16 chunks, 32 b); writes per-block partials P[blk][0:208]=s1, [208:416]=s2
__global__ __launch_bounds__(256) void k_stats(const float* __restrict__ pA,
                                               const float* __restrict__ pB,
                                               const float* __restrict__ cu,
                                               const float* __restrict__ base,
                                               const float* __restrict__ dist,
                                               const int* __restrict__ loc,
                                               float* __restrict__ P) {
  __shared__ float c_lds[16 * 64];
  __shared__ int loc_s[16];
  int t = threadIdx.x;
  int b = blockIdx.y;
  int n0 = blockIdx.x * 64;
  if (t < 16) loc_s[t] = loc[b * 16 + t];
  __syncthreads();
  for (int idx = t; idx < 1024; idx += 256) {
    int a = idx >> 6, nn = idx & 63;
    c_lds[idx] = dist[loc_s[a] * N_ + n0 + nn];
  }
  __syncthreads();
  int j = t;
  if (j < MID_) {
    float cuj = cu[j];
    float bj = base[j];
    float pre[16];
#pragma unroll
    for (int a = 0; a < 16; a++) pre[a] = pA[(b * 16 + a) * MID_ + j] + bj;
    float s1a = 0, s1b = 0, s1c = 0, s1d = 0;
    float s2a = 0, s2b = 0, s2c = 0, s2d = 0;
    for (int nn = 0; nn < 64; nn++) {
      float pb = pB[(size_t)(b * N_ + n0 + nn) * MID_ + j];
#pragma unroll
      for (int a = 0; a < 16; a += 4) {
        float h0 = fmaf(c_lds[(a + 0) * 64 + nn], cuj, pre[a + 0] + pb);
        float h1 = fmaf(c_lds[(a + 1) * 64 + nn], cuj, pre[a + 1] + pb);
        float h2 = fmaf(c_lds[(a + 2) * 64 + nn], cuj, pre[a + 2] + pb);
        float h3 = fmaf(c_lds[(a + 3) * 64 + nn], cuj, pre[a + 3] + pb);
        s1a += h0; s2a = fmaf(h0, h0, s2a);
        s1b += h1; s2b = fmaf(h1, h1, s2b);
        s1c += h2; s2c = fmaf(h2, h2, s2c);
        s1d += h3; s2d = fmaf(h3, h3, s2d);
      }
    }
    int blk = b * 16 + blockIdx.x;
    P[blk * 416 + j] = (s1a + s1b) + (s1c + s1d);
    P[blk * 416 + MID_ + j] = (s2a + s2b) + (s2c + s2d);
  }
}

__global__ __launch_bounds__(256) void k_bn(const float* __restrict__ P,
                                            const float* __restrict__ g,
                                            const float* __restrict__ bb,
                                            float* __restrict__ scale,
                                            float* __restrict__ shift) {
  int j = threadIdx.x;
  if (j >= MID_) return;
  double s1 = 0.0, s2 = 0.0;
  for (int k = 0; k < 512; k++) {
    s1 += (double)P[k * 416 + j];
    s2 += (double)P[k * 416 + MID_ + j];
  }
  float mu = (float)(s1 * (1.0 / (double)ROWS));
  float var = (float)(s2 * (1.0 / (double)ROWS) - (double)mu * (double)mu);
  float rs = rsqrtf(var + 1e-5f);
  float sc = rs * g[j];
  scale[j] = sc;
  shift[j] = bb[j] - mu * sc;
}

// ---------------- logits: wave per node, 16 agents inner ----------------
__global__ __launch_bounds__(256) void k_logits(const float* __restrict__ pA,
                                                const float* __restrict__ pB,
                                                const float* __restrict__ cu,
                                                const float* __restrict__ base,
                                                const float* __restrict__ scale,
                                                const float* __restrict__ shift,
                                                const float* __restrict__ W2,
                                                const float* __restrict__ b2,
                                                const float* __restrict__ dist,
                                                const int* __restrict__ loc,
                                                const int* __restrict__ mask,
                                                float* __restrict__ lg) {
  __shared__ float pA_s[16 * 256];
  __shared__ float cf[4 * 256];   // [scale | shift | cu | W2], zero-padded
  __shared__ int loc_s[16];
  int t = threadIdx.x;
  int b = blockIdx.y;
  int n0 = blockIdx.x * 16;
  for (int idx = t; idx < 16 * 256; idx += 256) {
    int a = idx >> 8, j = idx & 255;
    pA_s[idx] = (j < MID_) ? (pA[(b * 16 + a) * MID_ + j] + base[j]) : 0.f;
  }
  for (int idx = t; idx < 4 * 256; idx += 256) {
    int which = idx >> 8, j = idx & 255;
    float v = 0.f;
    if (j < MID_) {
      const float* p = (which == 0) ? scale : (which == 1) ? shift : (which == 2) ? cu : W2;
      v = p[j];
    }
    cf[idx] = v;
  }
  if (t < 16) loc_s[t] = loc[b * 16 + t];
  __syncthreads();
  int lane = t & 63, w = t >> 6;
  float b2v = b2[0];
  float cu0 = cf[512 + lane], cu1 = cf[512 + 64 + lane], cu2 = cf[512 + 128 + lane], cu3 = cf[512 + 192 + lane];
  float sc0 = cf[lane], sc1 = cf[64 + lane], sc2 = cf[128 + lane], sc3 = cf[192 + lane];
  float sh0 = cf[256 + lane], sh1 = cf[256 + 64 + lane], sh2 = cf[256 + 128 + lane], sh3 = cf[256 + 192 + lane];
  float w20 = cf[768 + lane], w21 = cf[768 + 64 + lane], w22 = cf[768 + 128 + lane], w23 = cf[768 + 192 + lane];
  for (int q = 0; q < 4; q++) {
    int n = n0 + w * 4 + q;
    float ca = (lane < 16) ? dist[loc_s[lane] * N_ + n] : 0.f;
    const float* pbp = pB + (size_t)(b * N_ + n) * MID_;
    float pb0 = pbp[lane];
    float pb1 = pbp[64 + lane];
    float pb2 = pbp[128 + lane];
    float pb3 = (lane < 16) ? pbp[192 + lane] : 0.f;
    for (int a = 0; a < 16; a++) {
      float c = __shfl(ca, a);
      float h0 = fmaf(c, cu0, pA_s[a * 256 + lane] + pb0);
      float h1 = fmaf(c, cu1, pA_s[a * 256 + 64 + lane] + pb1);
      float h2 = fmaf(c, cu2, pA_s[a * 256 + 128 + lane] + pb2);
      float h3 = fmaf(c, cu3, pA_s[a * 256 + 192 + lane] + pb3);
      h0 = fmaxf(fmaf(h0, sc0, sh0), 0.f);
      h1 = fmaxf(fmaf(h1, sc1, sh1), 0.f);
      h2 = fmaxf(fmaf(h2, sc2, sh2), 0.f);
      h3 = fmaxf(fmaf(h3, sc3, sh3), 0.f);
      float r = fmaf(h0, w20, fmaf(h1, w21, fmaf(h2, w22, h3 * w23)));
#pragma unroll
      for (int o = 32; o > 0; o >>= 1) r += __shfl_xor(r, o);
      if (lane == 0) {
        int oi = b * AN_ + a * N_ + n;
        lg[oi] = mask[oi] ? (r + b2v) : -1e8f;
      }
    }
  }
}

// ---------------- masked softmax over 16384 per batch ----------------
__global__ __launch_bounds__(1024) void k_softmax(const float* __restrict__ lg,
                                                  float* __restrict__ out) {
  __shared__ float red[16];
  __shared__ float bc[2];
  int b = blockIdx.x, t = threadIdx.x;
  const float* lb = lg + b * AN_;
  float v[16];
  float m = -3.0e38f;
#pragma unroll
  for (int i = 0; i < 16; i++) {
    v[i] = lb[i * 1024 + t];
    m = fmaxf(m, v[i]);
  }
#pragma unroll
  for (int o = 32; o > 0; o >>= 1) m = fmaxf(m, __shfl_xor(m, o));
  if ((t & 63) == 0) red[t >> 6] = m;
  __syncthreads();
  if (t == 0) {
    float mm = red[0];
    for (int i = 1; i < 16; i++) mm = fmaxf(mm, red[i]);
    bc[0] = mm;
  }
  __syncthreads();
  m = bc[0];
  float s = 0.f;
#pragma unroll
  for (int i = 0; i < 16; i++) {
    v[i] = expf(v[i] - m);
    s += v[i];
  }
#pragma unroll
  for (int o = 32; o > 0; o >>= 1) s += __shfl_xor(s, o);
  if ((t & 63) == 0) red[t >> 6] = s;
  __syncthreads();
  if (t == 0) {
    float ss = 0.f;
    for (int i = 0; i < 16; i++) ss += red[i];
    bc[1] = ss;
  }
  __syncthreads();
  float inv = 1.0f / bc[1];
#pragma unroll
  for (int i = 0; i < 16; i++) out[b * AN_ + i * 1024 + t] = v[i] * inv;
}

extern "C" void kernel_launch(void* const* d_in, const int* in_sizes, int n_in,
                              void* d_out, int out_size, void* d_ws, size_t ws_size,
                              hipStream_t stream) {
  const float* gn = (const float*)d_in[0];
  const int* el = (const int*)d_in[1];
  const int* loc = (const int*)d_in[2];
  const int* mask = (const int*)d_in[3];
  const float* dist = (const float*)d_in[4];
  const float* c0W = (const float*)d_in[5];
  const float* c0b = (const float*)d_in[6];
  const float* c0g = (const float*)d_in[7];
  const float* c0be = (const float*)d_in[8];
  const float* c1W = (const float*)d_in[9];
  const float* c1b = (const float*)d_in[10];
  const float* c1g = (const float*)d_in[11];
  const float* c1be = (const float*)d_in[12];
  const float* c2W = (const float*)d_in[13];
  const float* c2b = (const float*)d_in[14];
  const float* c2g = (const float*)d_in[15];
  const float* c2be = (const float*)d_in[16];
  const float* eW = (const float*)d_in[17];
  const float* eb = (const float*)d_in[18];
  const float* W1 = (const float*)d_in[19];
  const float* b1 = (const float*)d_in[20];
  const float* bng = (const float*)d_in[21];
  const float* bnb = (const float*)d_in[22];
  const float* W2 = (const float*)d_in[23];
  const float* b2 = (const float*)d_in[24];
  float* out = (float*)d_out;

  char* p = (char*)d_ws;
  auto alloc = [&](size_t bytes) {
    char* r = p;
    p += (bytes + 255) & ~(size_t)255;
    return r;
  };
  int* counts = (int*)alloc((size_t)NODES * 4);
  int* rowptr = (int*)alloc((size_t)NODES * 4);
  int* cursor = (int*)alloc((size_t)NODES * 4);
  int* ssrc = (int*)alloc((size_t)NEDGE * 4);
  float* xc = (float*)alloc((size_t)NODES * MID_ * 4);
  float* pB = (float*)alloc((size_t)NODES * MID_ * 4);
  float* pA = (float*)alloc((size_t)512 * MID_ * 4);
  float* cu = (float*)alloc(256 * 4);
  float* base = (float*)alloc(256 * 4);
  float* scale = (float*)alloc(256 * 4);
  float* shift = (float*)alloc(256 * 4);
  float* P = (float*)alloc((size_t)512 * 416 * 4);
  float* lg = (float*)alloc((size_t)ROWS * 4);

  hipMemsetAsync(counts, 0, (size_t)NODES * 4, stream);

  k_hist<<<512, 256, 0, stream>>>(el, counts);
  k_scan<<<1, 1024, 0, stream>>>(counts, rowptr, cursor);
  k_scatter<<<512, 256, 0, stream>>>(el, cursor, ssrc);

  k_layer<16, true><<<8192, 256, 0, stream>>>(gn, FIN_, 0, xc, 16, rowptr, counts, ssrc, c0W, c0b, c0g, c0be);
  k_layer<64, false><<<8192, 256, 0, stream>>>(xc, MID_, 16, xc, 80, rowptr, counts, ssrc, c1W, c1b, c1g, c1be);
  k_layer<64, false><<<8192, 256, 0, stream>>>(xc, MID_, 80, xc, 144, rowptr, counts, ssrc, c2W, c2b, c2g, c2be);

  k_pA<<<512, 256, 0, stream>>>(xc, loc, W1, pA);
  k_cu<<<1, 256, 0, stream>>>(W1, eW, eb, b1, cu, base);
  k_pB<<<512, 256, 0, stream>>>(xc, W1, pB);

  k_stats<<<dim3(16, 32), 256, 0, stream>>>(pA, pB, cu, base, dist, loc, P);
  k_bn<<<1, 256, 0, stream>>>(P, bng, bnb, scale, shift);

  k_logits<<<dim3(64, 32), 256, 0, stream>>>(pA, pB, cu, base, scale, shift, W2, b2, dist, loc, mask, lg);
  k_softmax<<<32, 1024, 0, stream>>>(lg, out);
}

// Round 2
// 441.324 us; speedup vs baseline: 1.1138x; 1.1138x over previous
//
#include <hip/hip_runtime.h>
#include <cstddef>

#define B_    32
#define N_    1024
#define E_    4096
#define A_    16
#define FIN_  16
#define H_    64
#define MID_  208
#define NODES (B_ * N_)      // 32768
#define NEDGE (B_ * E_)      // 131072
#define ROWS  (B_ * A_ * N_) // 524288
#define AN_   (A_ * N_)      // 16384

// ---------------- CSR build (edges keyed by dst) ----------------
__global__ __launch_bounds__(256) void k_hist(const int* __restrict__ el,
                                              int* __restrict__ counts) {
  int e = blockIdx.x * 256 + threadIdx.x;
  int b = e >> 12;
  int dl = el[b * (2 * E_) + E_ + (e & (E_ - 1))];
  atomicAdd(&counts[b * N_ + dl], 1);
}

__global__ __launch_bounds__(1024) void k_scan(const int* __restrict__ counts,
                                               int* __restrict__ rowptr,
                                               int* __restrict__ cursor) {
  __shared__ int part[1024];
  int t = threadIdx.x;
  int base = t * 32;
  int pre[32];
  int s = 0;
#pragma unroll
  for (int i = 0; i < 32; i++) { pre[i] = s; s += counts[base + i]; }
  part[t] = s;
  __syncthreads();
  for (int off = 1; off < 1024; off <<= 1) {
    int v = (t >= off) ? part[t - off] : 0;
    __syncthreads();
    part[t] += v;
    __syncthreads();
  }
  int prev = (t == 0) ? 0 : part[t - 1];
#pragma unroll
  for (int i = 0; i < 32; i++) {
    int r = prev + pre[i];
    rowptr[base + i] = r;
    cursor[base + i] = r;
  }
}

__global__ __launch_bounds__(256) void k_scatter(const int* __restrict__ el,
                                                 int* __restrict__ cursor,
                                                 int* __restrict__ ssrc) {
  int e = blockIdx.x * 256 + threadIdx.x;
  int b = e >> 12;
  int le = e & (E_ - 1);
  int sl = el[b * (2 * E_) + le];
  int dl = el[b * (2 * E_) + E_ + le];
  int pos = atomicAdd(&cursor[b * N_ + dl], 1);
  ssrc[pos] = b * N_ + sl;
}

// ---------------- GIN layer: wave per node ----------------
template <int FINT, bool COPYIN>
__global__ __launch_bounds__(256) void k_layer(const float* __restrict__ xin, int xstride, int in_off,
                                               float* __restrict__ xc, int out_off,
                                               const int* __restrict__ rowptr,
                                               const int* __restrict__ counts,
                                               const int* __restrict__ ssrc,
                                               const float* __restrict__ W,
                                               const float* __restrict__ bias,
                                               const float* __restrict__ g,
                                               const float* __restrict__ beta) {
  __shared__ float Ws[FINT * 64];
  __shared__ float aggs[4][64];
  int t = threadIdx.x;
  for (int i = t; i < FINT * 64; i += 256) Ws[i] = W[i];
  int lane = t & 63, w = t >> 6;
  int node = blockIdx.x * 4 + w;
  int r0 = rowptr[node];
  int deg = counts[node];
  float aggf = 0.f;
  if (lane < FINT) {
    for (int e = 0; e < deg; e++) {
      int s = ssrc[r0 + e];
      aggf += xin[s * xstride + in_off + lane];
    }
  }
  aggs[w][lane] = (lane < FINT) ? aggf : 0.f;
  __syncthreads();
  float y = bias[lane];
#pragma unroll
  for (int f = 0; f < FINT; f++) {
    y = fmaf(aggs[w][f], Ws[f * 64 + lane], y);
  }
  float m = y;
#pragma unroll
  for (int o = 32; o > 0; o >>= 1) m += __shfl_xor(m, o);
  m *= (1.f / 64.f);
  float d = y - m;
  float vv = d * d;
#pragma unroll
  for (int o = 32; o > 0; o >>= 1) vv += __shfl_xor(vv, o);
  vv *= (1.f / 64.f);
  float outv = fmaxf(d * rsqrtf(vv + 1e-5f) * g[lane] + beta[lane], 0.f);
  xc[node * MID_ + out_off + lane] = outv;
  if (COPYIN) {
    if (lane < FIN_) xc[node * MID_ + lane] = xin[node * FIN_ + lane];
  }
}

// ---------------- pA: 512 agent rows x W1[0:208] ----------------
__global__ __launch_bounds__(256) void k_pA(const float* __restrict__ xc,
                                            const int* __restrict__ loc,
                                            const float* __restrict__ W1,
                                            float* __restrict__ pA) {
  int blk = blockIdx.x;            // b*16 + a
  int b = blk >> 4;
  __shared__ float xr[MID_];
  int t = threadIdx.x;
  int node = b * N_ + loc[blk];
  if (t < MID_) xr[t] = xc[node * MID_ + t];
  __syncthreads();
  if (t < MID_) {
    float acc = 0.f;
    for (int i = 0; i < MID_; i++) acc = fmaf(xr[i], W1[i * MID_ + t], acc);
    pA[blk * MID_ + t] = acc;
  }
}

// ---------------- cu = eW @ W1[416:480], base = eb @ W1[416:480] + b1 ----------------
__global__ __launch_bounds__(256) void k_cu(const float* __restrict__ W1,
                                            const float* __restrict__ eW,
                                            const float* __restrict__ eb,
                                            const float* __restrict__ b1,
                                            float* __restrict__ cu,
                                            float* __restrict__ base) {
  int j = threadIdx.x;
  if (j < MID_) {
    float c = 0.f, bs = 0.f;
    for (int k = 0; k < H_; k++) {
      float w = W1[(2 * MID_ + k) * MID_ + j];
      c = fmaf(eW[k], w, c);
      bs = fmaf(eb[k], w, bs);
    }
    cu[j] = c;
    base[j] = bs + b1[j];
  }
}

// ---------------- pB GEMM (double-buffered): [32768,208] @ W1[208:416] -> pBT [208][32768] ----------------
#define ASTR 72
__global__ __launch_bounds__(256) void k_pB(const float* __restrict__ xc,
                                            const float* __restrict__ W1,
                                            float* __restrict__ pBT) {
  __shared__ float As[2][16 * ASTR];
  __shared__ float Bs[2][16 * 256];
  int t = threadIdx.x;
  int row0 = blockIdx.x * 64;
  int rm = t & 15, rn = t >> 4;
  int arow = t & 63, akq = t >> 6;
  float acc[4][16];
#pragma unroll
  for (int i = 0; i < 4; i++)
#pragma unroll
    for (int j = 0; j < 16; j++) acc[i][j] = 0.f;

  // prefetch tile 0
  float4 aV = *(const float4*)(xc + (size_t)(row0 + arow) * MID_ + akq * 4);
  float bV[16];
#pragma unroll
  for (int i = 0; i < 16; i++) bV[i] = (t < MID_) ? W1[(size_t)(MID_ + i) * MID_ + t] : 0.f;
  As[0][(akq * 4 + 0) * ASTR + arow] = aV.x;
  As[0][(akq * 4 + 1) * ASTR + arow] = aV.y;
  As[0][(akq * 4 + 2) * ASTR + arow] = aV.z;
  As[0][(akq * 4 + 3) * ASTR + arow] = aV.w;
#pragma unroll
  for (int i = 0; i < 16; i++) Bs[0][i * 256 + t] = bV[i];
  __syncthreads();

  for (int kt = 0; kt < 13; kt++) {
    int cur = kt & 1;
    float4 aN;
    float bN[16];
    if (kt < 12) {
      int k0 = (kt + 1) * 16;
      aN = *(const float4*)(xc + (size_t)(row0 + arow) * MID_ + k0 + akq * 4);
#pragma unroll
      for (int i = 0; i < 16; i++) bN[i] = (t < MID_) ? W1[(size_t)(MID_ + k0 + i) * MID_ + t] : 0.f;
    }
#pragma unroll 4
    for (int kk = 0; kk < 16; kk++) {
      float4 a4 = *(const float4*)&As[cur][kk * ASTR + rm * 4];
      const float* bp = &Bs[cur][kk * 256 + rn * 16];
      float4 b0 = *(const float4*)(bp);
      float4 b1v = *(const float4*)(bp + 4);
      float4 b2v = *(const float4*)(bp + 8);
      float4 b3v = *(const float4*)(bp + 12);
      float av[4] = {a4.x, a4.y, a4.z, a4.w};
      float bv[16] = {b0.x, b0.y, b0.z, b0.w, b1v.x, b1v.y, b1v.z, b1v.w,
                      b2v.x, b2v.y, b2v.z, b2v.w, b3v.x, b3v.y, b3v.z, b3v.w};
#pragma unroll
      for (int i = 0; i < 4; i++)
#pragma unroll
        for (int j = 0; j < 16; j++) acc[i][j] = fmaf(av[i], bv[j], acc[i][j]);
    }
    __syncthreads();
    if (kt < 12) {
      int nxt = cur ^ 1;
      As[nxt][(akq * 4 + 0) * ASTR + arow] = aN.x;
      As[nxt][(akq * 4 + 1) * ASTR + arow] = aN.y;
      As[nxt][(akq * 4 + 2) * ASTR + arow] = aN.z;
      As[nxt][(akq * 4 + 3) * ASTR + arow] = aN.w;
#pragma unroll
      for (int i = 0; i < 16; i++) Bs[nxt][i * 256 + t] = bN[i];
    }
    __syncthreads();
  }

  if (rn < 13) {
#pragma unroll
    for (int q = 0; q < 16; q++) {
      int j = rn * 16 + q;
      *(float4*)(pBT + (size_t)j * NODES + row0 + rm * 4) =
          make_float4(acc[0][q], acc[1][q], acc[2][q], acc[3][q]);
    }
  }
}

// ---------------- dist row sums: d1row[r] = sum_n dist[r][n], c2row[r] = sum dist^2 ----------------
__global__ __launch_bounds__(256) void k_d1(const float* __restrict__ dist,
                                            float* __restrict__ d1row,
                                            float* __restrict__ c2row) {
  int t = threadIdx.x, lane = t & 63, w = t >> 6;
  int r = blockIdx.x * 4 + w;
  const float* dr = dist + (size_t)r * N_;
  float s = 0.f, c2 = 0.f;
#pragma unroll
  for (int k = 0; k < 16; k++) {
    float v = dr[lane + 64 * k];
    s += v;
    c2 = fmaf(v, v, c2);
  }
#pragma unroll
  for (int o = 32; o > 0; o >>= 1) { s += __shfl_xor(s, o); c2 += __shfl_xor(c2, o); }
  if (lane == 0) { d1row[r] = s; c2row[r] = c2; }
}

// ---------------- e1[b][n] = sum_a dist[loc[b,a]][n] ----------------
__global__ __launch_bounds__(256) void k_csum(const float* __restrict__ dist,
                                              const int* __restrict__ loc,
                                              float* __restrict__ e1) {
  __shared__ int loc_s[16];
  int b = blockIdx.x, t = threadIdx.x;
  if (t < 16) loc_s[t] = loc[b * 16 + t];
  __syncthreads();
  float e4[4] = {0.f, 0.f, 0.f, 0.f};
  for (int a = 0; a < 16; a++) {
    const float* dr = dist + (size_t)loc_s[a] * N_;
#pragma unroll
    for (int k = 0; k < 4; k++) e4[k] += dr[t + 256 * k];
  }
#pragma unroll
  for (int k = 0; k < 4; k++) e1[b * N_ + t + 256 * k] = e4[k];
}

// ---------------- pB reductions per (j,b): S1=sum pb, S2=sum pb^2, SE=sum pb*e1 ----------------
__global__ __launch_bounds__(256) void k_pbred(const float* __restrict__ pBT,
                                               const float* __restrict__ e1,
                                               float* __restrict__ SB) {
  __shared__ float red[3][4];
  int j = blockIdx.x, b = blockIdx.y, t = threadIdx.x;
  const float* pr = pBT + (size_t)j * NODES + b * N_;
  const float* er = e1 + b * N_;
  float s1 = 0.f, s2 = 0.f, se = 0.f;
#pragma unroll
  for (int k = 0; k < 4; k++) {
    float v = pr[t + 256 * k];
    float e = er[t + 256 * k];
    s1 += v;
    s2 = fmaf(v, v, s2);
    se = fmaf(v, e, se);
  }
#pragma unroll
  for (int o = 32; o > 0; o >>= 1) {
    s1 += __shfl_xor(s1, o);
    s2 += __shfl_xor(s2, o);
    se += __shfl_xor(se, o);
  }
  if ((t & 63) == 0) { red[0][t >> 6] = s1; red[1][t >> 6] = s2; red[2][t >> 6] = se; }
  __syncthreads();
  if (t == 0) {
    SB[(b * 3 + 0) * MID_ + j] = red[0][0] + red[0][1] + red[0][2] + red[0][3];
    SB[(b * 3 + 1) * MID_ + j] = red[1][0] + red[1][1] + red[1][2] + red[1][3];
    SB[(b * 3 + 2) * MID_ + j] = red[2][0] + red[2][1] + red[2][2] + red[2][3];
  }
}

// ---------------- BN stats (exact separable algebra) + build va table & packs ----------------
__global__ __launch_bounds__(256) void k_bn(const float* __restrict__ pA,
                                            const float* __restrict__ cu,
                                            const float* __restrict__ base,
                                            const float* __restrict__ d1row,
                                            const float* __restrict__ c2row,
                                            const int* __restrict__ loc,
                                            const float* __restrict__ SB,
                                            const float* __restrict__ bng,
                                            const float* __restrict__ bnb,
                                            const float* __restrict__ W2,
                                            float* __restrict__ vaT,
                                            float* __restrict__ wpack4) {
  __shared__ float d1s[512];
  __shared__ float sred[8];
  int t = threadIdx.x;
  float p1 = 0.f, p2 = 0.f;
  for (int r = t; r < 512; r += 256) {
    int l = loc[r];
    float dv = d1row[l];
    float cv = c2row[l];
    d1s[r] = dv;
    p1 += dv;
    p2 += cv;
  }
#pragma unroll
  for (int o = 32; o > 0; o >>= 1) { p1 += __shfl_xor(p1, o); p2 += __shfl_xor(p2, o); }
  if ((t & 63) == 0) { sred[t >> 6] = p1; sred[4 + (t >> 6)] = p2; }
  __syncthreads();
  float Sc1 = sred[0] + sred[1] + sred[2] + sred[3];
  float Sc2 = sred[4] + sred[5] + sred[6] + sred[7];
  int j = t;
  if (j < MID_) {
    float cuj = cu[j], bj = base[j];
    double t1 = 0, t2 = 0, t3 = 0, cross = 0, spb1 = 0, spb2 = 0, spbe = 0;
    for (int b = 0; b < 32; b++) {
      float sab = 0.f;
#pragma unroll 4
      for (int a = 0; a < 16; a++) {
        int r = b * 16 + a;
        float pa = pA[r * MID_ + j] + bj;
        t1 += pa;
        t2 += (double)pa * pa;
        t3 += (double)pa * d1s[r];
        sab += pa;
      }
      double s1b = SB[(b * 3 + 0) * MID_ + j];
      cross += (double)sab * s1b;
      spb1 += s1b;
      spb2 += SB[(b * 3 + 1) * MID_ + j];
      spbe += SB[(b * 3 + 2) * MID_ + j];
    }
    double s1 = 1024.0 * t1 + 16.0 * spb1 + (double)cuj * Sc1;
    double s2 = 1024.0 * t2 + 16.0 * spb2 + (double)cuj * cuj * Sc2 +
                2.0 * (cross + (double)cuj * (t3 + spbe));
    double mu = s1 * (1.0 / (double)ROWS);
    double var = s2 * (1.0 / (double)ROWS) - mu * mu;
    float sc = (float)(1.0 / sqrt(var + 1e-5)) * bng[j];
    float sh = bnb[j] - (float)mu * sc;
    wpack4[4 * j + 0] = sc;
    wpack4[4 * j + 1] = cuj * sc;
    wpack4[4 * j + 2] = W2[j];
    wpack4[4 * j + 3] = 0.f;
    for (int r = 0; r < 512; r++) {
      float pa = pA[r * MID_ + j] + bj;
      vaT[((size_t)(r >> 4) * MID_ + j) * 16 + (r & 15)] = pa * sc + sh;
    }
  }
}

// ---------------- logits: node-per-lane, j-split across 4 waves ----------------
__global__ __launch_bounds__(256) void k_logits(const float* __restrict__ pBT,
                                                const float* __restrict__ vaT,
                                                const float* __restrict__ wpack4,
                                                const float* __restrict__ dist,
                                                const int* __restrict__ loc,
                                                const int* __restrict__ mask,
                                                const float* __restrict__ b2,
                                                float* __restrict__ lg) {
  __shared__ float accL[4][16][64];
  __shared__ int loc_s[16];
  int t = threadIdx.x, lane = t & 63, w = t >> 6;
  int b = blockIdx.y, n0 = blockIdx.x * 64;
  if (t < 16) loc_s[t] = loc[b * 16 + t];
  __syncthreads();
  float c[16];
#pragma unroll
  for (int a = 0; a < 16; a++) c[a] = dist[(size_t)loc_s[a] * N_ + n0 + lane];
  float acc[16];
#pragma unroll
  for (int a = 0; a < 16; a++) acc[a] = 0.f;
  int ng = b * N_ + n0 + lane;
  const float4* wp = (const float4*)wpack4;
  int j0 = w * 52;
#pragma unroll 4
  for (int jj = 0; jj < 52; jj++) {
    int j = j0 + jj;
    float pbv = pBT[(size_t)j * NODES + ng];
    float4 wv = wp[j];
    float pbs = pbv * wv.x;
    const float* va = vaT + ((size_t)b * MID_ + j) * 16;
#pragma unroll
    for (int a = 0; a < 16; a++) {
      float h = fmaf(c[a], wv.y, va[a] + pbs);
      h = fmaxf(h, 0.f);
      acc[a] = fmaf(h, wv.z, acc[a]);
    }
  }
#pragma unroll
  for (int a = 0; a < 16; a++) accL[w][a][lane] = acc[a];
  __syncthreads();
  float b2v = b2[0];
#pragma unroll
  for (int p = 0; p < 4; p++) {
    int idx = p * 256 + t;
    int a = idx >> 6, nn = idx & 63;
    float s = accL[0][a][nn] + accL[1][a][nn] + accL[2][a][nn] + accL[3][a][nn] + b2v;
    int oi = b * AN_ + a * N_ + n0 + nn;
    lg[oi] = mask[oi] ? s : -1e8f;
  }
}

// ---------------- softmax, 2-phase ----------------
__global__ __launch_bounds__(256) void k_sm1(const float* __restrict__ lg,
                                             float2* __restrict__ P) {
  __shared__ float red[4];
  __shared__ float redS[4];
  int b = blockIdx.y, x = blockIdx.x, t = threadIdx.x;
  const float* lb = lg + b * AN_ + x * 2048;
  float v[8];
  float m = -3.0e38f;
#pragma unroll
  for (int k = 0; k < 8; k++) {
    v[k] = lb[t + 256 * k];
    m = fmaxf(m, v[k]);
  }
#pragma unroll
  for (int o = 32; o > 0; o >>= 1) m = fmaxf(m, __shfl_xor(m, o));
  if ((t & 63) == 0) red[t >> 6] = m;
  __syncthreads();
  m = fmaxf(fmaxf(red[0], red[1]), fmaxf(red[2], red[3]));
  float s = 0.f;
#pragma unroll
  for (int k = 0; k < 8; k++) s += expf(v[k] - m);
#pragma unroll
  for (int o = 32; o > 0; o >>= 1) s += __shfl_xor(s, o);
  if ((t & 63) == 0) redS[t >> 6] = s;
  __syncthreads();
  if (t == 0) P[b * 8 + x] = make_float2(m, redS[0] + redS[1] + redS[2] + redS[3]);
}

__global__ __launch_bounds__(256) void k_sm2(const float* __restrict__ lg,
                                             const float2* __restrict__ P,
                                             float* __restrict__ out) {
  int b = blockIdx.y, x = blockIdx.x, t = threadIdx.x;
  float M = -3.0e38f;
  float2 pr[8];
#pragma unroll
  for (int k = 0; k < 8; k++) {
    pr[k] = P[b * 8 + k];
    M = fmaxf(M, pr[k].x);
  }
  float S = 0.f;
#pragma unroll
  for (int k = 0; k < 8; k++) S += pr[k].y * expf(pr[k].x - M);
  float inv = 1.0f / S;
  const float* lb = lg + b * AN_ + x * 2048;
  float* ob = out + b * AN_ + x * 2048;
#pragma unroll
  for (int k = 0; k < 8; k++) ob[t + 256 * k] = expf(lb[t + 256 * k] - M) * inv;
}

extern "C" void kernel_launch(void* const* d_in, const int* in_sizes, int n_in,
                              void* d_out, int out_size, void* d_ws, size_t ws_size,
                              hipStream_t stream) {
  const float* gn = (const float*)d_in[0];
  const int* el = (const int*)d_in[1];
  const int* loc = (const int*)d_in[2];
  const int* mask = (const int*)d_in[3];
  const float* dist = (const float*)d_in[4];
  const float* c0W = (const float*)d_in[5];
  const float* c0b = (const float*)d_in[6];
  const float* c0g = (const float*)d_in[7];
  const float* c0be = (const float*)d_in[8];
  const float* c1W = (const float*)d_in[9];
  const float* c1b = (const float*)d_in[10];
  const float* c1g = (const float*)d_in[11];
  const float* c1be = (const float*)d_in[12];
  const float* c2W = (const float*)d_in[13];
  const float* c2b = (const float*)d_in[14];
  const float* c2g = (const float*)d_in[15];
  const float* c2be = (const float*)d_in[16];
  const float* eW = (const float*)d_in[17];
  const float* eb = (const float*)d_in[18];
  const float* W1 = (const float*)d_in[19];
  const float* b1 = (const float*)d_in[20];
  const float* bng = (const float*)d_in[21];
  const float* bnb = (const float*)d_in[22];
  const float* W2 = (const float*)d_in[23];
  const float* b2 = (const float*)d_in[24];
  float* out = (float*)d_out;

  char* p = (char*)d_ws;
  auto alloc = [&](size_t bytes) {
    char* r = p;
    p += (bytes + 255) & ~(size_t)255;
    return r;
  };
  int* counts = (int*)alloc((size_t)NODES * 4);
  int* rowptr = (int*)alloc((size_t)NODES * 4);
  int* cursor = (int*)alloc((size_t)NODES * 4);
  int* ssrc = (int*)alloc((size_t)NEDGE * 4);
  float* xc = (float*)alloc((size_t)NODES * MID_ * 4);
  float* pBT = (float*)alloc((size_t)NODES * MID_ * 4);
  float* pA = (float*)alloc((size_t)512 * MID_ * 4);
  float* cu = (float*)alloc(256 * 4);
  float* base = (float*)alloc(256 * 4);
  float* d1row = (float*)alloc((size_t)N_ * 4);
  float* c2row = (float*)alloc((size_t)N_ * 4);
  float* e1 = (float*)alloc((size_t)B_ * N_ * 4);
  float* SB = (float*)alloc((size_t)B_ * 3 * MID_ * 4);
  float* vaT = (float*)alloc((size_t)B_ * MID_ * 16 * 4);
  float* wpack4 = (float*)alloc((size_t)MID_ * 4 * 4);
  float* lg = (float*)alloc((size_t)ROWS * 4);
  float2* Psm = (float2*)alloc((size_t)256 * 8);

  hipMemsetAsync(counts, 0, (size_t)NODES * 4, stream);

  k_hist<<<512, 256, 0, stream>>>(el, counts);
  k_scan<<<1, 1024, 0, stream>>>(counts, rowptr, cursor);
  k_scatter<<<512, 256, 0, stream>>>(el, cursor, ssrc);

  k_layer<16, true><<<8192, 256, 0, stream>>>(gn, FIN_, 0, xc, 16, rowptr, counts, ssrc, c0W, c0b, c0g, c0be);
  k_layer<64, false><<<8192, 256, 0, stream>>>(xc, MID_, 16, xc, 80, rowptr, counts, ssrc, c1W, c1b, c1g, c1be);
  k_layer<64, false><<<8192, 256, 0, stream>>>(xc, MID_, 80, xc, 144, rowptr, counts, ssrc, c2W, c2b, c2g, c2be);

  k_pA<<<512, 256, 0, stream>>>(xc, loc, W1, pA);
  k_cu<<<1, 256, 0, stream>>>(W1, eW, eb, b1, cu, base);
  k_pB<<<512, 256, 0, stream>>>(xc, W1, pBT);

  k_d1<<<256, 256, 0, stream>>>(dist, d1row, c2row);
  k_csum<<<32, 256, 0, stream>>>(dist, loc, e1);
  k_pbred<<<dim3(MID_, 32), 256, 0, stream>>>(pBT, e1, SB);
  k_bn<<<1, 256, 0, stream>>>(pA, cu, base, d1row, c2row, loc, SB, bng, bnb, W2, vaT, wpack4);

  k_logits<<<dim3(16, 32), 256, 0, stream>>>(pBT, vaT, wpack4, dist, loc, mask, b2, lg);
  k_sm1<<<dim3(8, 32), 256, 0, stream>>>(lg, Psm);
  k_sm2<<<dim3(8, 32), 256, 0, stream>>>(lg, Psm, out);
}

// Round 3
// 350.357 us; speedup vs baseline: 1.4030x; 1.2596x over previous
//
#include <hip/hip_runtime.h>
#include <cstddef>

#define B_    32
#define N_    1024
#define E_    4096
#define A_    16
#define FIN_  16
#define H_    64
#define MID_  208
#define NODES (B_ * N_)      // 32768
#define NEDGE (B_ * E_)      // 131072
#define ROWS  (B_ * A_ * N_) // 524288
#define AN_   (A_ * N_)      // 16384

// ---------------- CSR build (edges keyed by dst) ----------------
__global__ __launch_bounds__(256) void k_hist(const int* __restrict__ el,
                                              int* __restrict__ counts) {
  int e = blockIdx.x * 256 + threadIdx.x;
  int b = e >> 12;
  int dl = el[b * (2 * E_) + E_ + (e & (E_ - 1))];
  atomicAdd(&counts[b * N_ + dl], 1);
}

__global__ __launch_bounds__(1024) void k_scan(const int* __restrict__ counts,
                                               int* __restrict__ rowptr,
                                               int* __restrict__ cursor) {
  __shared__ int part[1024];
  int t = threadIdx.x;
  int base = t * 32;
  int pre[32];
  int s = 0;
#pragma unroll
  for (int i = 0; i < 32; i++) { pre[i] = s; s += counts[base + i]; }
  part[t] = s;
  __syncthreads();
  for (int off = 1; off < 1024; off <<= 1) {
    int v = (t >= off) ? part[t - off] : 0;
    __syncthreads();
    part[t] += v;
    __syncthreads();
  }
  int prev = (t == 0) ? 0 : part[t - 1];
#pragma unroll
  for (int i = 0; i < 32; i++) {
    int r = prev + pre[i];
    rowptr[base + i] = r;
    cursor[base + i] = r;
  }
}

__global__ __launch_bounds__(256) void k_scatter(const int* __restrict__ el,
                                                 int* __restrict__ cursor,
                                                 int* __restrict__ ssrc) {
  int e = blockIdx.x * 256 + threadIdx.x;
  int b = e >> 12;
  int le = e & (E_ - 1);
  int sl = el[b * (2 * E_) + le];
  int dl = el[b * (2 * E_) + E_ + le];
  int pos = atomicAdd(&cursor[b * N_ + dl], 1);
  ssrc[pos] = b * N_ + sl;
}

// ---------------- GIN layer: wave per node ----------------
template <int FINT, bool COPYIN>
__global__ __launch_bounds__(256) void k_layer(const float* __restrict__ xin, int xstride, int in_off,
                                               float* __restrict__ xc, int out_off,
                                               const int* __restrict__ rowptr,
                                               const int* __restrict__ counts,
                                               const int* __restrict__ ssrc,
                                               const float* __restrict__ W,
                                               const float* __restrict__ bias,
                                               const float* __restrict__ g,
                                               const float* __restrict__ beta) {
  __shared__ float Ws[FINT * 64];
  __shared__ float aggs[4][64];
  int t = threadIdx.x;
  for (int i = t; i < FINT * 64; i += 256) Ws[i] = W[i];
  int lane = t & 63, w = t >> 6;
  int node = blockIdx.x * 4 + w;
  int r0 = rowptr[node];
  int deg = counts[node];
  float aggf = 0.f;
  if (lane < FINT) {
    for (int e = 0; e < deg; e++) {
      int s = ssrc[r0 + e];
      aggf += xin[s * xstride + in_off + lane];
    }
  }
  aggs[w][lane] = (lane < FINT) ? aggf : 0.f;
  __syncthreads();
  float y = bias[lane];
#pragma unroll
  for (int f = 0; f < FINT; f++) {
    y = fmaf(aggs[w][f], Ws[f * 64 + lane], y);
  }
  float m = y;
#pragma unroll
  for (int o = 32; o > 0; o >>= 1) m += __shfl_xor(m, o);
  m *= (1.f / 64.f);
  float d = y - m;
  float vv = d * d;
#pragma unroll
  for (int o = 32; o > 0; o >>= 1) vv += __shfl_xor(vv, o);
  vv *= (1.f / 64.f);
  float outv = fmaxf(d * rsqrtf(vv + 1e-5f) * g[lane] + beta[lane], 0.f);
  xc[node * MID_ + out_off + lane] = outv;
  if (COPYIN) {
    if (lane < FIN_) xc[node * MID_ + lane] = xin[node * FIN_ + lane];
  }
}

// ---------------- pA: 512 agent rows x W1[0:208] ----------------
__global__ __launch_bounds__(256) void k_pA(const float* __restrict__ xc,
                                            const int* __restrict__ loc,
                                            const float* __restrict__ W1,
                                            float* __restrict__ pA) {
  int blk = blockIdx.x;            // b*16 + a
  int b = blk >> 4;
  __shared__ float xr[MID_];
  int t = threadIdx.x;
  int node = b * N_ + loc[blk];
  if (t < MID_) xr[t] = xc[node * MID_ + t];
  __syncthreads();
  if (t < MID_) {
    float acc = 0.f;
    for (int i = 0; i < MID_; i++) acc = fmaf(xr[i], W1[i * MID_ + t], acc);
    pA[blk * MID_ + t] = acc;
  }
}

// ---------------- cu = eW @ W1[416:480], base = eb @ W1[416:480] + b1 ----------------
__global__ __launch_bounds__(256) void k_cu(const float* __restrict__ W1,
                                            const float* __restrict__ eW,
                                            const float* __restrict__ eb,
                                            const float* __restrict__ b1,
                                            float* __restrict__ cu,
                                            float* __restrict__ base) {
  int j = threadIdx.x;
  if (j < MID_) {
    float c = 0.f, bs = 0.f;
    for (int k = 0; k < H_; k++) {
      float w = W1[(2 * MID_ + k) * MID_ + j];
      c = fmaf(eW[k], w, c);
      bs = fmaf(eb[k], w, bs);
    }
    cu[j] = c;
    base[j] = bs + b1[j];
  }
}

// ---------------- pB GEMM (double-buffered): [32768,208] @ W1[208:416] -> pBT [208][32768] ----------------
#define ASTR 72
__global__ __launch_bounds__(256) void k_pB(const float* __restrict__ xc,
                                            const float* __restrict__ W1,
                                            float* __restrict__ pBT) {
  __shared__ float As[2][16 * ASTR];
  __shared__ float Bs[2][16 * 256];
  int t = threadIdx.x;
  int row0 = blockIdx.x * 64;
  int rm = t & 15, rn = t >> 4;
  int arow = t & 63, akq = t >> 6;
  float acc[4][16];
#pragma unroll
  for (int i = 0; i < 4; i++)
#pragma unroll
    for (int j = 0; j < 16; j++) acc[i][j] = 0.f;

  float4 aV = *(const float4*)(xc + (size_t)(row0 + arow) * MID_ + akq * 4);
  float bV[16];
#pragma unroll
  for (int i = 0; i < 16; i++) bV[i] = (t < MID_) ? W1[(size_t)(MID_ + i) * MID_ + t] : 0.f;
  As[0][(akq * 4 + 0) * ASTR + arow] = aV.x;
  As[0][(akq * 4 + 1) * ASTR + arow] = aV.y;
  As[0][(akq * 4 + 2) * ASTR + arow] = aV.z;
  As[0][(akq * 4 + 3) * ASTR + arow] = aV.w;
#pragma unroll
  for (int i = 0; i < 16; i++) Bs[0][i * 256 + t] = bV[i];
  __syncthreads();

  for (int kt = 0; kt < 13; kt++) {
    int cur = kt & 1;
    float4 aN;
    float bN[16];
    if (kt < 12) {
      int k0 = (kt + 1) * 16;
      aN = *(const float4*)(xc + (size_t)(row0 + arow) * MID_ + k0 + akq * 4);
#pragma unroll
      for (int i = 0; i < 16; i++) bN[i] = (t < MID_) ? W1[(size_t)(MID_ + k0 + i) * MID_ + t] : 0.f;
    }
#pragma unroll 4
    for (int kk = 0; kk < 16; kk++) {
      float4 a4 = *(const float4*)&As[cur][kk * ASTR + rm * 4];
      const float* bp = &Bs[cur][kk * 256 + rn * 16];
      float4 b0 = *(const float4*)(bp);
      float4 b1v = *(const float4*)(bp + 4);
      float4 b2v = *(const float4*)(bp + 8);
      float4 b3v = *(const float4*)(bp + 12);
      float av[4] = {a4.x, a4.y, a4.z, a4.w};
      float bv[16] = {b0.x, b0.y, b0.z, b0.w, b1v.x, b1v.y, b1v.z, b1v.w,
                      b2v.x, b2v.y, b2v.z, b2v.w, b3v.x, b3v.y, b3v.z, b3v.w};
#pragma unroll
      for (int i = 0; i < 4; i++)
#pragma unroll
        for (int j = 0; j < 16; j++) acc[i][j] = fmaf(av[i], bv[j], acc[i][j]);
    }
    __syncthreads();
    if (kt < 12) {
      int nxt = cur ^ 1;
      As[nxt][(akq * 4 + 0) * ASTR + arow] = aN.x;
      As[nxt][(akq * 4 + 1) * ASTR + arow] = aN.y;
      As[nxt][(akq * 4 + 2) * ASTR + arow] = aN.z;
      As[nxt][(akq * 4 + 3) * ASTR + arow] = aN.w;
#pragma unroll
      for (int i = 0; i < 16; i++) Bs[nxt][i * 256 + t] = bN[i];
    }
    __syncthreads();
  }

  if (rn < 13) {
#pragma unroll
    for (int q = 0; q < 16; q++) {
      int j = rn * 16 + q;
      *(float4*)(pBT + (size_t)j * NODES + row0 + rm * 4) =
          make_float4(acc[0][q], acc[1][q], acc[2][q], acc[3][q]);
    }
  }
}

// ---------------- dist row sums ----------------
__global__ __launch_bounds__(256) void k_d1(const float* __restrict__ dist,
                                            float* __restrict__ d1row,
                                            float* __restrict__ c2row) {
  int t = threadIdx.x, lane = t & 63, w = t >> 6;
  int r = blockIdx.x * 4 + w;
  const float* dr = dist + (size_t)r * N_;
  float s = 0.f, c2 = 0.f;
#pragma unroll
  for (int k = 0; k < 16; k++) {
    float v = dr[lane + 64 * k];
    s += v;
    c2 = fmaf(v, v, c2);
  }
#pragma unroll
  for (int o = 32; o > 0; o >>= 1) { s += __shfl_xor(s, o); c2 += __shfl_xor(c2, o); }
  if (lane == 0) { d1row[r] = s; c2row[r] = c2; }
}

// ---------------- e1[b][n] = sum_a dist[loc[b,a]][n] ----------------
__global__ __launch_bounds__(256) void k_csum(const float* __restrict__ dist,
                                              const int* __restrict__ loc,
                                              float* __restrict__ e1) {
  __shared__ int loc_s[16];
  int b = blockIdx.x, t = threadIdx.x;
  if (t < 16) loc_s[t] = loc[b * 16 + t];
  __syncthreads();
  float e4[4] = {0.f, 0.f, 0.f, 0.f};
  for (int a = 0; a < 16; a++) {
    const float* dr = dist + (size_t)loc_s[a] * N_;
#pragma unroll
    for (int k = 0; k < 4; k++) e4[k] += dr[t + 256 * k];
  }
#pragma unroll
  for (int k = 0; k < 4; k++) e1[b * N_ + t + 256 * k] = e4[k];
}

// ---------------- pB reductions per (j,b): S1, S2, SE ----------------
__global__ __launch_bounds__(256) void k_pbred(const float* __restrict__ pBT,
                                               const float* __restrict__ e1,
                                               float* __restrict__ SB) {
  __shared__ float red[3][4];
  int j = blockIdx.x, b = blockIdx.y, t = threadIdx.x;
  const float* pr = pBT + (size_t)j * NODES + b * N_;
  const float* er = e1 + b * N_;
  float s1 = 0.f, s2 = 0.f, se = 0.f;
#pragma unroll
  for (int k = 0; k < 4; k++) {
    float v = pr[t + 256 * k];
    float e = er[t + 256 * k];
    s1 += v;
    s2 = fmaf(v, v, s2);
    se = fmaf(v, e, se);
  }
#pragma unroll
  for (int o = 32; o > 0; o >>= 1) {
    s1 += __shfl_xor(s1, o);
    s2 += __shfl_xor(s2, o);
    se += __shfl_xor(se, o);
  }
  if ((t & 63) == 0) { red[0][t >> 6] = s1; red[1][t >> 6] = s2; red[2][t >> 6] = se; }
  __syncthreads();
  if (t == 0) {
    SB[(b * 3 + 0) * MID_ + j] = red[0][0] + red[0][1] + red[0][2] + red[0][3];
    SB[(b * 3 + 1) * MID_ + j] = red[1][0] + red[1][1] + red[1][2] + red[1][3];
    SB[(b * 3 + 2) * MID_ + j] = red[2][0] + red[2][1] + red[2][2] + red[2][3];
  }
}

// ---------------- BN per-batch partials of the pA terms ----------------
// Pb[b][0][j]=sum_a pa, [1]=sum pa^2, [2]=sum pa*d1row[loc]
__global__ __launch_bounds__(256) void k_bnpart(const float* __restrict__ pA,
                                                const float* __restrict__ base,
                                                const float* __restrict__ d1row,
                                                const int* __restrict__ loc,
                                                float* __restrict__ Pb) {
  __shared__ float d1s[16];
  int b = blockIdx.x, t = threadIdx.x;
  if (t < 16) d1s[t] = d1row[loc[b * 16 + t]];
  __syncthreads();
  int j = t;
  if (j < MID_) {
    float bj = base[j];
    float t1 = 0.f, t2 = 0.f, t3 = 0.f;
#pragma unroll 4
    for (int a = 0; a < 16; a++) {
      float pa = pA[(b * 16 + a) * MID_ + j] + bj;
      t1 += pa;
      t2 = fmaf(pa, pa, t2);
      t3 = fmaf(pa, d1s[a], t3);
    }
    Pb[(b * 3 + 0) * MID_ + j] = t1;
    Pb[(b * 3 + 1) * MID_ + j] = t2;
    Pb[(b * 3 + 2) * MID_ + j] = t3;
  }
}

// ---------------- BN finalize: combine partials, emit scale/shift/wpack ----------------
__global__ __launch_bounds__(256) void k_bnfin(const float* __restrict__ Pb,
                                               const float* __restrict__ SB,
                                               const float* __restrict__ cu,
                                               const float* __restrict__ d1row,
                                               const float* __restrict__ c2row,
                                               const int* __restrict__ loc,
                                               const float* __restrict__ bng,
                                               const float* __restrict__ bnb,
                                               const float* __restrict__ W2,
                                               float* __restrict__ scale,
                                               float* __restrict__ shift,
                                               float* __restrict__ wpack4) {
  __shared__ float sred[8];
  int t = threadIdx.x;
  float p1 = 0.f, p2 = 0.f;
  for (int r = t; r < 512; r += 256) {
    int l = loc[r];
    p1 += d1row[l];
    p2 += c2row[l];
  }
#pragma unroll
  for (int o = 32; o > 0; o >>= 1) { p1 += __shfl_xor(p1, o); p2 += __shfl_xor(p2, o); }
  if ((t & 63) == 0) { sred[t >> 6] = p1; sred[4 + (t >> 6)] = p2; }
  __syncthreads();
  float Sc1 = sred[0] + sred[1] + sred[2] + sred[3];
  float Sc2 = sred[4] + sred[5] + sred[6] + sred[7];
  int j = t;
  if (j < MID_) {
    float cuj = cu[j];
    double t1 = 0, t2 = 0, t3 = 0, cross = 0, spb1 = 0, spb2 = 0, spbe = 0;
    for (int b = 0; b < 32; b++) {
      float q1 = Pb[(b * 3 + 0) * MID_ + j];
      float q2 = Pb[(b * 3 + 1) * MID_ + j];
      float q3 = Pb[(b * 3 + 2) * MID_ + j];
      float s1b = SB[(b * 3 + 0) * MID_ + j];
      float s2b = SB[(b * 3 + 1) * MID_ + j];
      float seb = SB[(b * 3 + 2) * MID_ + j];
      t1 += q1; t2 += q2; t3 += q3;
      cross += (double)q1 * s1b;
      spb1 += s1b; spb2 += s2b; spbe += seb;
    }
    double s1 = 1024.0 * t1 + 16.0 * spb1 + (double)cuj * Sc1;
    double s2 = 1024.0 * t2 + 16.0 * spb2 + (double)cuj * cuj * Sc2 +
                2.0 * (cross + (double)cuj * (t3 + spbe));
    double mu = s1 * (1.0 / (double)ROWS);
    double var = s2 * (1.0 / (double)ROWS) - mu * mu;
    float sc = (float)(1.0 / sqrt(var + 1e-5)) * bng[j];
    float sh = bnb[j] - (float)mu * sc;
    scale[j] = sc;
    shift[j] = sh;
    wpack4[4 * j + 0] = sc;
    wpack4[4 * j + 1] = cuj * sc;
    wpack4[4 * j + 2] = W2[j];
    wpack4[4 * j + 3] = 0.f;
  }
}

// ---------------- vaT build: grid over b, coalesced pA reads, float4 writes ----------------
__global__ __launch_bounds__(256) void k_va(const float* __restrict__ pA,
                                            const float* __restrict__ base,
                                            const float* __restrict__ scale,
                                            const float* __restrict__ shift,
                                            float* __restrict__ vaT) {
  int b = blockIdx.x, j = threadIdx.x;
  if (j >= MID_) return;
  float bj = base[j], sc = scale[j], sh = shift[j];
  float v[16];
#pragma unroll 4
  for (int a = 0; a < 16; a++) {
    float pa = pA[(b * 16 + a) * MID_ + j] + bj;
    v[a] = pa * sc + sh;
  }
  float* dst = vaT + ((size_t)b * MID_ + j) * 16;
#pragma unroll
  for (int q = 0; q < 4; q++)
    *(float4*)(dst + q * 4) = make_float4(v[q * 4], v[q * 4 + 1], v[q * 4 + 2], v[q * 4 + 3]);
}

// ---------------- logits: node-per-lane, j-split across 4 waves ----------------
__global__ __launch_bounds__(256) void k_logits(const float* __restrict__ pBT,
                                                const float* __restrict__ vaT,
                                                const float* __restrict__ wpack4,
                                                const float* __restrict__ dist,
                                                const int* __restrict__ loc,
                                                const int* __restrict__ mask,
                                                const float* __restrict__ b2,
                                                float* __restrict__ lg) {
  __shared__ float accL[4][16][64];
  __shared__ int loc_s[16];
  int t = threadIdx.x, lane = t & 63, w = t >> 6;
  int b = blockIdx.y, n0 = blockIdx.x * 64;
  if (t < 16) loc_s[t] = loc[b * 16 + t];
  __syncthreads();
  float c[16];
#pragma unroll
  for (int a = 0; a < 16; a++) c[a] = dist[(size_t)loc_s[a] * N_ + n0 + lane];
  float acc[16];
#pragma unroll
  for (int a = 0; a < 16; a++) acc[a] = 0.f;
  int ng = b * N_ + n0 + lane;
  const float4* wp = (const float4*)wpack4;
  int j0 = w * 52;
#pragma unroll 4
  for (int jj = 0; jj < 52; jj++) {
    int j = j0 + jj;
    float pbv = pBT[(size_t)j * NODES + ng];
    float4 wv = wp[j];
    float pbs = pbv * wv.x;
    const float* va = vaT + ((size_t)b * MID_ + j) * 16;
#pragma unroll
    for (int a = 0; a < 16; a++) {
      float h = fmaf(c[a], wv.y, va[a] + pbs);
      h = fmaxf(h, 0.f);
      acc[a] = fmaf(h, wv.z, acc[a]);
    }
  }
#pragma unroll
  for (int a = 0; a < 16; a++) accL[w][a][lane] = acc[a];
  __syncthreads();
  float b2v = b2[0];
#pragma unroll
  for (int p = 0; p < 4; p++) {
    int idx = p * 256 + t;
    int a = idx >> 6, nn = idx & 63;
    float s = accL[0][a][nn] + accL[1][a][nn] + accL[2][a][nn] + accL[3][a][nn] + b2v;
    int oi = b * AN_ + a * N_ + n0 + nn;
    lg[oi] = mask[oi] ? s : -1e8f;
  }
}

// ---------------- softmax, 2-phase ----------------
__global__ __launch_bounds__(256) void k_sm1(const float* __restrict__ lg,
                                             float2* __restrict__ P) {
  __shared__ float red[4];
  __shared__ float redS[4];
  int b = blockIdx.y, x = blockIdx.x, t = threadIdx.x;
  const float* lb = lg + b * AN_ + x * 2048;
  float v[8];
  float m = -3.0e38f;
#pragma unroll
  for (int k = 0; k < 8; k++) {
    v[k] = lb[t + 256 * k];
    m = fmaxf(m, v[k]);
  }
#pragma unroll
  for (int o = 32; o > 0; o >>= 1) m = fmaxf(m, __shfl_xor(m, o));
  if ((t & 63) == 0) red[t >> 6] = m;
  __syncthreads();
  m = fmaxf(fmaxf(red[0], red[1]), fmaxf(red[2], red[3]));
  float s = 0.f;
#pragma unroll
  for (int k = 0; k < 8; k++) s += expf(v[k] - m);
#pragma unroll
  for (int o = 32; o > 0; o >>= 1) s += __shfl_xor(s, o);
  if ((t & 63) == 0) redS[t >> 6] = s;
  __syncthreads();
  if (t == 0) P[b * 8 + x] = make_float2(m, redS[0] + redS[1] + redS[2] + redS[3]);
}

__global__ __launch_bounds__(256) void k_sm2(const float* __restrict__ lg,
                                             const float2* __restrict__ P,
                                             float* __restrict__ out) {
  int b = blockIdx.y, x = blockIdx.x, t = threadIdx.x;
  float M = -3.0e38f;
  float2 pr[8];
#pragma unroll
  for (int k = 0; k < 8; k++) {
    pr[k] = P[b * 8 + k];
    M = fmaxf(M, pr[k].x);
  }
  float S = 0.f;
#pragma unroll
  for (int k = 0; k < 8; k++) S += pr[k].y * expf(pr[k].x - M);
  float inv = 1.0f / S;
  const float* lb = lg + b * AN_ + x * 2048;
  float* ob = out + b * AN_ + x * 2048;
#pragma unroll
  for (int k = 0; k < 8; k++) ob[t + 256 * k] = expf(lb[t + 256 * k] - M) * inv;
}

extern "C" void kernel_launch(void* const* d_in, const int* in_sizes, int n_in,
                              void* d_out, int out_size, void* d_ws, size_t ws_size,
                              hipStream_t stream) {
  const float* gn = (const float*)d_in[0];
  const int* el = (const int*)d_in[1];
  const int* loc = (const int*)d_in[2];
  const int* mask = (const int*)d_in[3];
  const float* dist = (const float*)d_in[4];
  const float* c0W = (const float*)d_in[5];
  const float* c0b = (const float*)d_in[6];
  const float* c0g = (const float*)d_in[7];
  const float* c0be = (const float*)d_in[8];
  const float* c1W = (const float*)d_in[9];
  const float* c1b = (const float*)d_in[10];
  const float* c1g = (const float*)d_in[11];
  const float* c1be = (const float*)d_in[12];
  const float* c2W = (const float*)d_in[13];
  const float* c2b = (const float*)d_in[14];
  const float* c2g = (const float*)d_in[15];
  const float* c2be = (const float*)d_in[16];
  const float* eW = (const float*)d_in[17];
  const float* eb = (const float*)d_in[18];
  const float* W1 = (const float*)d_in[19];
  const float* b1 = (const float*)d_in[20];
  const float* bng = (const float*)d_in[21];
  const float* bnb = (const float*)d_in[22];
  const float* W2 = (const float*)d_in[23];
  const float* b2 = (const float*)d_in[24];
  float* out = (float*)d_out;

  char* p = (char*)d_ws;
  auto alloc = [&](size_t bytes) {
    char* r = p;
    p += (bytes + 255) & ~(size_t)255;
    return r;
  };
  int* counts = (int*)alloc((size_t)NODES * 4);
  int* rowptr = (int*)alloc((size_t)NODES * 4);
  int* cursor = (int*)alloc((size_t)NODES * 4);
  int* ssrc = (int*)alloc((size_t)NEDGE * 4);
  float* xc = (float*)alloc((size_t)NODES * MID_ * 4);
  float* pBT = (float*)alloc((size_t)NODES * MID_ * 4);
  float* pA = (float*)alloc((size_t)512 * MID_ * 4);
  float* cu = (float*)alloc(256 * 4);
  float* base = (float*)alloc(256 * 4);
  float* d1row = (float*)alloc((size_t)N_ * 4);
  float* c2row = (float*)alloc((size_t)N_ * 4);
  float* e1 = (float*)alloc((size_t)B_ * N_ * 4);
  float* SB = (float*)alloc((size_t)B_ * 3 * MID_ * 4);
  float* Pb = (float*)alloc((size_t)B_ * 3 * MID_ * 4);
  float* scale = (float*)alloc(256 * 4);
  float* shift = (float*)alloc(256 * 4);
  float* vaT = (float*)alloc((size_t)B_ * MID_ * 16 * 4);
  float* wpack4 = (float*)alloc((size_t)MID_ * 4 * 4);
  float* lg = (float*)alloc((size_t)ROWS * 4);
  float2* Psm = (float2*)alloc((size_t)256 * 8);

  hipMemsetAsync(counts, 0, (size_t)NODES * 4, stream);

  k_hist<<<512, 256, 0, stream>>>(el, counts);
  k_scan<<<1, 1024, 0, stream>>>(counts, rowptr, cursor);
  k_scatter<<<512, 256, 0, stream>>>(el, cursor, ssrc);

  k_layer<16, true><<<8192, 256, 0, stream>>>(gn, FIN_, 0, xc, 16, rowptr, counts, ssrc, c0W, c0b, c0g, c0be);
  k_layer<64, false><<<8192, 256, 0, stream>>>(xc, MID_, 16, xc, 80, rowptr, counts, ssrc, c1W, c1b, c1g, c1be);
  k_layer<64, false><<<8192, 256, 0, stream>>>(xc, MID_, 80, xc, 144, rowptr, counts, ssrc, c2W, c2b, c2g, c2be);

  k_pA<<<512, 256, 0, stream>>>(xc, loc, W1, pA);
  k_cu<<<1, 256, 0, stream>>>(W1, eW, eb, b1, cu, base);
  k_pB<<<512, 256, 0, stream>>>(xc, W1, pBT);

  k_d1<<<256, 256, 0, stream>>>(dist, d1row, c2row);
  k_csum<<<32, 256, 0, stream>>>(dist, loc, e1);
  k_pbred<<<dim3(MID_, 32), 256, 0, stream>>>(pBT, e1, SB);
  k_bnpart<<<32, 256, 0, stream>>>(pA, base, d1row, loc, Pb);
  k_bnfin<<<1, 256, 0, stream>>>(Pb, SB, cu, d1row, c2row, loc, bng, bnb, W2, scale, shift, wpack4);
  k_va<<<32, 256, 0, stream>>>(pA, base, scale, shift, vaT);

  k_logits<<<dim3(16, 32), 256, 0, stream>>>(pBT, vaT, wpack4, dist, loc, mask, b2, lg);
  k_sm1<<<dim3(8, 32), 256, 0, stream>>>(lg, Psm);
  k_sm2<<<dim3(8, 32), 256, 0, stream>>>(lg, Psm, out);
}

// Round 4
// 340.648 us; speedup vs baseline: 1.4430x; 1.0285x over previous
//
#include <hip/hip_runtime.h>
#include <cstddef>

#define B_    32
#define N_    1024
#define E_    4096
#define A_    16
#define FIN_  16
#define H_    64
#define MID_  208
#define NODES (B_ * N_)      // 32768
#define NEDGE (B_ * E_)      // 131072
#define ROWS  (B_ * A_ * N_) // 524288
#define AN_   (A_ * N_)      // 16384

__device__ __forceinline__ float readlane_f(float v, int l) {
  return __uint_as_float(__builtin_amdgcn_readlane(__float_as_uint(v), l));
}

// ---------------- CSR build (edges keyed by dst) ----------------
__global__ __launch_bounds__(256) void k_hist(const int* __restrict__ el,
                                              int* __restrict__ counts) {
  int e = blockIdx.x * 256 + threadIdx.x;
  int b = e >> 12;
  int dl = el[b * (2 * E_) + E_ + (e & (E_ - 1))];
  atomicAdd(&counts[b * N_ + dl], 1);
}

// per-graph scan: 32 blocks, each scans 1024 counts; base = b*4096
__global__ __launch_bounds__(256) void k_scan(const int* __restrict__ counts,
                                              int* __restrict__ rowptr,
                                              int* __restrict__ cursor) {
  __shared__ int part[256];
  int b = blockIdx.x, t = threadIdx.x;
  int4 c = *(const int4*)&counts[b * 1024 + t * 4];
  int s = c.x + c.y + c.z + c.w;
  part[t] = s;
  __syncthreads();
  for (int off = 1; off < 256; off <<= 1) {
    int v = (t >= off) ? part[t - off] : 0;
    __syncthreads();
    part[t] += v;
    __syncthreads();
  }
  int prev = ((t == 0) ? 0 : part[t - 1]) + b * E_;
  int p0 = prev, p1 = p0 + c.x, p2 = p1 + c.y, p3 = p2 + c.z;
  int4 r = make_int4(p0, p1, p2, p3);
  *(int4*)&rowptr[b * 1024 + t * 4] = r;
  *(int4*)&cursor[b * 1024 + t * 4] = r;
}

__global__ __launch_bounds__(256) void k_scatter(const int* __restrict__ el,
                                                 int* __restrict__ cursor,
                                                 int* __restrict__ ssrc) {
  int e = blockIdx.x * 256 + threadIdx.x;
  int b = e >> 12;
  int le = e & (E_ - 1);
  int sl = el[b * (2 * E_) + le];
  int dl = el[b * (2 * E_) + E_ + le];
  int pos = atomicAdd(&cursor[b * N_ + dl], 1);
  ssrc[pos] = b * N_ + sl;
}

// ---------------- GIN layer: wave per 4 nodes, register matvec, no LDS ----------------
template <int FINT, bool COPYIN>
__global__ __launch_bounds__(256) void k_layer(const float* __restrict__ xin, int xstride, int in_off,
                                               float* __restrict__ xc, int out_off,
                                               const int* __restrict__ rowptr,
                                               const int* __restrict__ counts,
                                               const int* __restrict__ ssrc,
                                               const float* __restrict__ W,
                                               const float* __restrict__ bias,
                                               const float* __restrict__ g,
                                               const float* __restrict__ beta) {
  int t = threadIdx.x, lane = t & 63, w = t >> 6;
  // W column in registers: Wcol[f] = W[f][lane]
  float Wcol[FINT];
#pragma unroll
  for (int f = 0; f < FINT; f++) Wcol[f] = W[f * 64 + lane];
  float bv = bias[lane], gv = g[lane], bev = beta[lane];
  constexpr int CH = 64 / FINT;                 // gather chunks per feature
  int f = lane & (FINT - 1);
  int ch = (FINT == 64) ? 0 : (lane >> 4);
  int nbase = (blockIdx.x * 4 + w) * 4;
  for (int nn = 0; nn < 4; nn++) {
    int node = nbase + nn;
    int r0 = rowptr[node];
    int deg = counts[node];
    float aggf = 0.f;
    for (int e = ch; e < deg; e += CH) {
      int s = ssrc[r0 + e];
      aggf += xin[(size_t)s * xstride + in_off + f];
    }
    float y = bv;
#pragma unroll
    for (int l = 0; l < 64; l++) {
      float av = readlane_f(aggf, l);
      y = fmaf(av, Wcol[l & (FINT - 1)], y);
    }
    // LayerNorm over the 64 lanes
    float m = y;
#pragma unroll
    for (int o = 32; o > 0; o >>= 1) m += __shfl_xor(m, o);
    m *= (1.f / 64.f);
    float d = y - m;
    float vv = d * d;
#pragma unroll
    for (int o = 32; o > 0; o >>= 1) vv += __shfl_xor(vv, o);
    vv *= (1.f / 64.f);
    float outv = fmaxf(d * rsqrtf(vv + 1e-5f) * gv + bev, 0.f);
    xc[(size_t)node * MID_ + out_off + lane] = outv;
    if (COPYIN) {
      if (lane < FIN_) xc[(size_t)node * MID_ + lane] = xin[(size_t)node * FIN_ + lane];
    }
  }
}

// ---------------- pA: 512 agent rows x W1[0:208] ----------------
__global__ __launch_bounds__(256) void k_pA(const float* __restrict__ xc,
                                            const int* __restrict__ loc,
                                            const float* __restrict__ W1,
                                            float* __restrict__ pA) {
  int blk = blockIdx.x;            // b*16 + a
  int b = blk >> 4;
  __shared__ float xr[MID_];
  int t = threadIdx.x;
  int node = b * N_ + loc[blk];
  if (t < MID_) xr[t] = xc[node * MID_ + t];
  __syncthreads();
  if (t < MID_) {
    float acc = 0.f;
    for (int i = 0; i < MID_; i++) acc = fmaf(xr[i], W1[i * MID_ + t], acc);
    pA[blk * MID_ + t] = acc;
  }
}

// ---------------- cu = eW @ W1[416:480], base = eb @ W1[416:480] + b1 ----------------
__global__ __launch_bounds__(256) void k_cu(const float* __restrict__ W1,
                                            const float* __restrict__ eW,
                                            const float* __restrict__ eb,
                                            const float* __restrict__ b1,
                                            float* __restrict__ cu,
                                            float* __restrict__ base) {
  int j = threadIdx.x;
  if (j < MID_) {
    float c = 0.f, bs = 0.f;
    for (int k = 0; k < H_; k++) {
      float w = W1[(2 * MID_ + k) * MID_ + j];
      c = fmaf(eW[k], w, c);
      bs = fmaf(eb[k], w, bs);
    }
    cu[j] = c;
    base[j] = bs + b1[j];
  }
}

// ---------------- pB GEMM (LDS-free, scalar-A): [32768,208] @ W1[208:416] -> pBT [208][32768] ----------------
// lane = j-quad (j0 = 4*lane, 52 active), wave = 16-row strip; A via uniform s_load, B via coalesced float4.
__global__ __launch_bounds__(256) void k_pB(const float* __restrict__ xc,
                                            const float* __restrict__ W1,
                                            float* __restrict__ pBT) {
  int t = threadIdx.x;
  int lane = t & 63;
  int w = __builtin_amdgcn_readfirstlane(t >> 6);     // wave-uniform
  int row0 = blockIdx.x * 64 + w * 16;
  int j0 = lane * 4;
  const float* Bbase = W1 + (size_t)MID_ * MID_;
  const float* Arow = xc + (size_t)row0 * MID_;

  float acc[16][4];
#pragma unroll
  for (int r = 0; r < 16; r++)
#pragma unroll
    for (int q = 0; q < 4; q++) acc[r][q] = 0.f;

#pragma unroll 2
  for (int c = 0; c < 52; c++) {
    int k = c * 4;
    // A: 16 rows x 4 k, wave-uniform -> scalar loads
    float4 a[16];
    const float* ap = Arow + k;
#pragma unroll
    for (int r = 0; r < 16; r++) a[r] = *(const float4*)(ap + r * MID_);
    // B: 4 k-rows, 4 j per lane (coalesced)
#pragma unroll
    for (int q = 0; q < 4; q++) {
      float4 bq = *(const float4*)(Bbase + (size_t)(k + q) * MID_ + j0);
#pragma unroll
      for (int r = 0; r < 16; r++) {
        float ar = (q == 0) ? a[r].x : (q == 1) ? a[r].y : (q == 2) ? a[r].z : a[r].w;
        acc[r][0] = fmaf(ar, bq.x, acc[r][0]);
        acc[r][1] = fmaf(ar, bq.y, acc[r][1]);
        acc[r][2] = fmaf(ar, bq.z, acc[r][2]);
        acc[r][3] = fmaf(ar, bq.w, acc[r][3]);
      }
    }
  }

  if (j0 < MID_) {
#pragma unroll
    for (int q = 0; q < 4; q++) {
      float* dst = pBT + (size_t)(j0 + q) * NODES + row0;
#pragma unroll
      for (int rq = 0; rq < 4; rq++) {
        *(float4*)(dst + rq * 4) = make_float4(acc[rq * 4 + 0][q], acc[rq * 4 + 1][q],
                                               acc[rq * 4 + 2][q], acc[rq * 4 + 3][q]);
      }
    }
  }
}

// ---------------- dist row sums ----------------
__global__ __launch_bounds__(256) void k_d1(const float* __restrict__ dist,
                                            float* __restrict__ d1row,
                                            float* __restrict__ c2row) {
  int t = threadIdx.x, lane = t & 63, w = t >> 6;
  int r = blockIdx.x * 4 + w;
  const float* dr = dist + (size_t)r * N_;
  float s = 0.f, c2 = 0.f;
#pragma unroll
  for (int k = 0; k < 16; k++) {
    float v = dr[lane + 64 * k];
    s += v;
    c2 = fmaf(v, v, c2);
  }
#pragma unroll
  for (int o = 32; o > 0; o >>= 1) { s += __shfl_xor(s, o); c2 += __shfl_xor(c2, o); }
  if (lane == 0) { d1row[r] = s; c2row[r] = c2; }
}

// ---------------- e1[b][n] = sum_a dist[loc[b,a]][n] ----------------
__global__ __launch_bounds__(256) void k_csum(const float* __restrict__ dist,
                                              const int* __restrict__ loc,
                                              float* __restrict__ e1) {
  __shared__ int loc_s[16];
  int b = blockIdx.x, t = threadIdx.x;
  if (t < 16) loc_s[t] = loc[b * 16 + t];
  __syncthreads();
  float e4[4] = {0.f, 0.f, 0.f, 0.f};
  for (int a = 0; a < 16; a++) {
    const float* dr = dist + (size_t)loc_s[a] * N_;
#pragma unroll
    for (int k = 0; k < 4; k++) e4[k] += dr[t + 256 * k];
  }
#pragma unroll
  for (int k = 0; k < 4; k++) e1[b * N_ + t + 256 * k] = e4[k];
}

// ---------------- pB reductions per (j,b): S1, S2, SE ----------------
__global__ __launch_bounds__(256) void k_pbred(const float* __restrict__ pBT,
                                               const float* __restrict__ e1,
                                               float* __restrict__ SB) {
  __shared__ float red[3][4];
  int j = blockIdx.x, b = blockIdx.y, t = threadIdx.x;
  const float* pr = pBT + (size_t)j * NODES + b * N_;
  const float* er = e1 + b * N_;
  float s1 = 0.f, s2 = 0.f, se = 0.f;
#pragma unroll
  for (int k = 0; k < 4; k++) {
    float v = pr[t + 256 * k];
    float e = er[t + 256 * k];
    s1 += v;
    s2 = fmaf(v, v, s2);
    se = fmaf(v, e, se);
  }
#pragma unroll
  for (int o = 32; o > 0; o >>= 1) {
    s1 += __shfl_xor(s1, o);
    s2 += __shfl_xor(s2, o);
    se += __shfl_xor(se, o);
  }
  if ((t & 63) == 0) { red[0][t >> 6] = s1; red[1][t >> 6] = s2; red[2][t >> 6] = se; }
  __syncthreads();
  if (t == 0) {
    SB[(b * 3 + 0) * MID_ + j] = red[0][0] + red[0][1] + red[0][2] + red[0][3];
    SB[(b * 3 + 1) * MID_ + j] = red[1][0] + red[1][1] + red[1][2] + red[1][3];
    SB[(b * 3 + 2) * MID_ + j] = red[2][0] + red[2][1] + red[2][2] + red[2][3];
  }
}

// ---------------- BN per-batch partials of the pA terms ----------------
__global__ __launch_bounds__(256) void k_bnpart(const float* __restrict__ pA,
                                                const float* __restrict__ base,
                                                const float* __restrict__ d1row,
                                                const int* __restrict__ loc,
                                                float* __restrict__ Pb) {
  __shared__ float d1s[16];
  int b = blockIdx.x, t = threadIdx.x;
  if (t < 16) d1s[t] = d1row[loc[b * 16 + t]];
  __syncthreads();
  int j = t;
  if (j < MID_) {
    float bj = base[j];
    float t1 = 0.f, t2 = 0.f, t3 = 0.f;
#pragma unroll 4
    for (int a = 0; a < 16; a++) {
      float pa = pA[(b * 16 + a) * MID_ + j] + bj;
      t1 += pa;
      t2 = fmaf(pa, pa, t2);
      t3 = fmaf(pa, d1s[a], t3);
    }
    Pb[(b * 3 + 0) * MID_ + j] = t1;
    Pb[(b * 3 + 1) * MID_ + j] = t2;
    Pb[(b * 3 + 2) * MID_ + j] = t3;
  }
}

// ---------------- BN finalize ----------------
__global__ __launch_bounds__(256) void k_bnfin(const float* __restrict__ Pb,
                                               const float* __restrict__ SB,
                                               const float* __restrict__ cu,
                                               const float* __restrict__ d1row,
                                               const float* __restrict__ c2row,
                                               const int* __restrict__ loc,
                                               const float* __restrict__ bng,
                                               const float* __restrict__ bnb,
                                               const float* __restrict__ W2,
                                               float* __restrict__ scale,
                                               float* __restrict__ shift,
                                               float* __restrict__ wpack4) {
  __shared__ float sred[8];
  int t = threadIdx.x;
  float p1 = 0.f, p2 = 0.f;
  for (int r = t; r < 512; r += 256) {
    int l = loc[r];
    p1 += d1row[l];
    p2 += c2row[l];
  }
#pragma unroll
  for (int o = 32; o > 0; o >>= 1) { p1 += __shfl_xor(p1, o); p2 += __shfl_xor(p2, o); }
  if ((t & 63) == 0) { sred[t >> 6] = p1; sred[4 + (t >> 6)] = p2; }
  __syncthreads();
  float Sc1 = sred[0] + sred[1] + sred[2] + sred[3];
  float Sc2 = sred[4] + sred[5] + sred[6] + sred[7];
  int j = t;
  if (j < MID_) {
    float cuj = cu[j];
    double t1 = 0, t2 = 0, t3 = 0, cross = 0, spb1 = 0, spb2 = 0, spbe = 0;
    for (int b = 0; b < 32; b++) {
      float q1 = Pb[(b * 3 + 0) * MID_ + j];
      float q2 = Pb[(b * 3 + 1) * MID_ + j];
      float q3 = Pb[(b * 3 + 2) * MID_ + j];
      float s1b = SB[(b * 3 + 0) * MID_ + j];
      float s2b = SB[(b * 3 + 1) * MID_ + j];
      float seb = SB[(b * 3 + 2) * MID_ + j];
      t1 += q1; t2 += q2; t3 += q3;
      cross += (double)q1 * s1b;
      spb1 += s1b; spb2 += s2b; spbe += seb;
    }
    double s1 = 1024.0 * t1 + 16.0 * spb1 + (double)cuj * Sc1;
    double s2 = 1024.0 * t2 + 16.0 * spb2 + (double)cuj * cuj * Sc2 +
                2.0 * (cross + (double)cuj * (t3 + spbe));
    double mu = s1 * (1.0 / (double)ROWS);
    double var = s2 * (1.0 / (double)ROWS) - mu * mu;
    float sc = (float)(1.0 / sqrt(var + 1e-5)) * bng[j];
    float sh = bnb[j] - (float)mu * sc;
    scale[j] = sc;
    shift[j] = sh;
    wpack4[4 * j + 0] = sc;
    wpack4[4 * j + 1] = cuj * sc;
    wpack4[4 * j + 2] = W2[j];
    wpack4[4 * j + 3] = 0.f;
  }
}

// ---------------- vaT build ----------------
__global__ __launch_bounds__(256) void k_va(const float* __restrict__ pA,
                                            const float* __restrict__ base,
                                            const float* __restrict__ scale,
                                            const float* __restrict__ shift,
                                            float* __restrict__ vaT) {
  int b = blockIdx.x, j = threadIdx.x;
  if (j >= MID_) return;
  float bj = base[j], sc = scale[j], sh = shift[j];
  float v[16];
#pragma unroll 4
  for (int a = 0; a < 16; a++) {
    float pa = pA[(b * 16 + a) * MID_ + j] + bj;
    v[a] = pa * sc + sh;
  }
  float* dst = vaT + ((size_t)b * MID_ + j) * 16;
#pragma unroll
  for (int q = 0; q < 4; q++)
    *(float4*)(dst + q * 4) = make_float4(v[q * 4], v[q * 4 + 1], v[q * 4 + 2], v[q * 4 + 3]);
}

// ---------------- logits: node-per-lane, j-split across 4 waves ----------------
__global__ __launch_bounds__(256) void k_logits(const float* __restrict__ pBT,
                                                const float* __restrict__ vaT,
                                                const float* __restrict__ wpack4,
                                                const float* __restrict__ dist,
                                                const int* __restrict__ loc,
                                                const int* __restrict__ mask,
                                                const float* __restrict__ b2,
                                                float* __restrict__ lg) {
  __shared__ float accL[4][16][64];
  __shared__ int loc_s[16];
  int t = threadIdx.x, lane = t & 63, w = t >> 6;
  int b = blockIdx.y, n0 = blockIdx.x * 64;
  if (t < 16) loc_s[t] = loc[b * 16 + t];
  __syncthreads();
  float c[16];
#pragma unroll
  for (int a = 0; a < 16; a++) c[a] = dist[(size_t)loc_s[a] * N_ + n0 + lane];
  float acc[16];
#pragma unroll
  for (int a = 0; a < 16; a++) acc[a] = 0.f;
  int ng = b * N_ + n0 + lane;
  const float4* wp = (const float4*)wpack4;
  int j0 = w * 52;
#pragma unroll 4
  for (int jj = 0; jj < 52; jj++) {
    int j = j0 + jj;
    float pbv = pBT[(size_t)j * NODES + ng];
    float4 wv = wp[j];
    float pbs = pbv * wv.x;
    const float* va = vaT + ((size_t)b * MID_ + j) * 16;
#pragma unroll
    for (int a = 0; a < 16; a++) {
      float h = fmaf(c[a], wv.y, va[a] + pbs);
      h = fmaxf(h, 0.f);
      acc[a] = fmaf(h, wv.z, acc[a]);
    }
  }
#pragma unroll
  for (int a = 0; a < 16; a++) accL[w][a][lane] = acc[a];
  __syncthreads();
  float b2v = b2[0];
#pragma unroll
  for (int p = 0; p < 4; p++) {
    int idx = p * 256 + t;
    int a = idx >> 6, nn = idx & 63;
    float s = accL[0][a][nn] + accL[1][a][nn] + accL[2][a][nn] + accL[3][a][nn] + b2v;
    int oi = b * AN_ + a * N_ + n0 + nn;
    lg[oi] = mask[oi] ? s : -1e8f;
  }
}

// ---------------- softmax, 2-phase ----------------
__global__ __launch_bounds__(256) void k_sm1(const float* __restrict__ lg,
                                             float2* __restrict__ P) {
  __shared__ float red[4];
  __shared__ float redS[4];
  int b = blockIdx.y, x = blockIdx.x, t = threadIdx.x;
  const float* lb = lg + b * AN_ + x * 2048;
  float v[8];
  float m = -3.0e38f;
#pragma unroll
  for (int k = 0; k < 8; k++) {
    v[k] = lb[t + 256 * k];
    m = fmaxf(m, v[k]);
  }
#pragma unroll
  for (int o = 32; o > 0; o >>= 1) m = fmaxf(m, __shfl_xor(m, o));
  if ((t & 63) == 0) red[t >> 6] = m;
  __syncthreads();
  m = fmaxf(fmaxf(red[0], red[1]), fmaxf(red[2], red[3]));
  float s = 0.f;
#pragma unroll
  for (int k = 0; k < 8; k++) s += expf(v[k] - m);
#pragma unroll
  for (int o = 32; o > 0; o >>= 1) s += __shfl_xor(s, o);
  if ((t & 63) == 0) redS[t >> 6] = s;
  __syncthreads();
  if (t == 0) P[b * 8 + x] = make_float2(m, redS[0] + redS[1] + redS[2] + redS[3]);
}

__global__ __launch_bounds__(256) void k_sm2(const float* __restrict__ lg,
                                             const float2* __restrict__ P,
                                             float* __restrict__ out) {
  int b = blockIdx.y, x = blockIdx.x, t = threadIdx.x;
  float M = -3.0e38f;
  float2 pr[8];
#pragma unroll
  for (int k = 0; k < 8; k++) {
    pr[k] = P[b * 8 + k];
    M = fmaxf(M, pr[k].x);
  }
  float S = 0.f;
#pragma unroll
  for (int k = 0; k < 8; k++) S += pr[k].y * expf(pr[k].x - M);
  float inv = 1.0f / S;
  const float* lb = lg + b * AN_ + x * 2048;
  float* ob = out + b * AN_ + x * 2048;
#pragma unroll
  for (int k = 0; k < 8; k++) ob[t + 256 * k] = expf(lb[t + 256 * k] - M) * inv;
}

extern "C" void kernel_launch(void* const* d_in, const int* in_sizes, int n_in,
                              void* d_out, int out_size, void* d_ws, size_t ws_size,
                              hipStream_t stream) {
  const float* gn = (const float*)d_in[0];
  const int* el = (const int*)d_in[1];
  const int* loc = (const int*)d_in[2];
  const int* mask = (const int*)d_in[3];
  const float* dist = (const float*)d_in[4];
  const float* c0W = (const float*)d_in[5];
  const float* c0b = (const float*)d_in[6];
  const float* c0g = (const float*)d_in[7];
  const float* c0be = (const float*)d_in[8];
  const float* c1W = (const float*)d_in[9];
  const float* c1b = (const float*)d_in[10];
  const float* c1g = (const float*)d_in[11];
  const float* c1be = (const float*)d_in[12];
  const float* c2W = (const float*)d_in[13];
  const float* c2b = (const float*)d_in[14];
  const float* c2g = (const float*)d_in[15];
  const float* c2be = (const float*)d_in[16];
  const float* eW = (const float*)d_in[17];
  const float* eb = (const float*)d_in[18];
  const float* W1 = (const float*)d_in[19];
  const float* b1 = (const float*)d_in[20];
  const float* bng = (const float*)d_in[21];
  const float* bnb = (const float*)d_in[22];
  const float* W2 = (const float*)d_in[23];
  const float* b2 = (const float*)d_in[24];
  float* out = (float*)d_out;

  char* p = (char*)d_ws;
  auto alloc = [&](size_t bytes) {
    char* r = p;
    p += (bytes + 255) & ~(size_t)255;
    return r;
  };
  int* counts = (int*)alloc((size_t)NODES * 4);
  int* rowptr = (int*)alloc((size_t)NODES * 4);
  int* cursor = (int*)alloc((size_t)NODES * 4);
  int* ssrc = (int*)alloc((size_t)NEDGE * 4);
  float* xc = (float*)alloc((size_t)NODES * MID_ * 4);
  float* pBT = (float*)alloc((size_t)NODES * MID_ * 4);
  float* pA = (float*)alloc((size_t)512 * MID_ * 4);
  float* cu = (float*)alloc(256 * 4);
  float* base = (float*)alloc(256 * 4);
  float* d1row = (float*)alloc((size_t)N_ * 4);
  float* c2row = (float*)alloc((size_t)N_ * 4);
  float* e1 = (float*)alloc((size_t)B_ * N_ * 4);
  float* SB = (float*)alloc((size_t)B_ * 3 * MID_ * 4);
  float* Pb = (float*)alloc((size_t)B_ * 3 * MID_ * 4);
  float* scale = (float*)alloc(256 * 4);
  float* shift = (float*)alloc(256 * 4);
  float* vaT = (float*)alloc((size_t)B_ * MID_ * 16 * 4);
  float* wpack4 = (float*)alloc((size_t)MID_ * 4 * 4);
  float* lg = (float*)alloc((size_t)ROWS * 4);
  float2* Psm = (float2*)alloc((size_t)256 * 8);

  hipMemsetAsync(counts, 0, (size_t)NODES * 4, stream);

  k_hist<<<512, 256, 0, stream>>>(el, counts);
  k_scan<<<32, 256, 0, stream>>>(counts, rowptr, cursor);
  k_scatter<<<512, 256, 0, stream>>>(el, cursor, ssrc);

  k_layer<16, true><<<2048, 256, 0, stream>>>(gn, FIN_, 0, xc, 16, rowptr, counts, ssrc, c0W, c0b, c0g, c0be);
  k_layer<64, false><<<2048, 256, 0, stream>>>(xc, MID_, 16, xc, 80, rowptr, counts, ssrc, c1W, c1b, c1g, c1be);
  k_layer<64, false><<<2048, 256, 0, stream>>>(xc, MID_, 80, xc, 144, rowptr, counts, ssrc, c2W, c2b, c2g, c2be);

  k_pA<<<512, 256, 0, stream>>>(xc, loc, W1, pA);
  k_cu<<<1, 256, 0, stream>>>(W1, eW, eb, b1, cu, base);
  k_pB<<<512, 256, 0, stream>>>(xc, W1, pBT);

  k_d1<<<256, 256, 0, stream>>>(dist, d1row, c2row);
  k_csum<<<32, 256, 0, stream>>>(dist, loc, e1);
  k_pbred<<<dim3(MID_, 32), 256, 0, stream>>>(pBT, e1, SB);
  k_bnpart<<<32, 256, 0, stream>>>(pA, base, d1row, loc, Pb);
  k_bnfin<<<1, 256, 0, stream>>>(Pb, SB, cu, d1row, c2row, loc, bng, bnb, W2, scale, shift, wpack4);
  k_va<<<32, 256, 0, stream>>>(pA, base, scale, shift, vaT);

  k_logits<<<dim3(16, 32), 256, 0, stream>>>(pBT, vaT, wpack4, dist, loc, mask, b2, lg);
  k_sm1<<<dim3(8, 32), 256, 0, stream>>>(lg, Psm);
  k_sm2<<<dim3(8, 32), 256, 0, stream>>>(lg, Psm, out);
}